// Round 4
// baseline (27651.785 us; speedup 1.0000x reference)
//
#include <hip/hip_runtime.h>

#define NS 1024
#define NH 64
#define NB 16384

// ---- XLA-CPU fp32 op clones (no FP contraction: __fmul_rn/__fadd_rn) ----

// Clone of XLA GenerateVF32Exp (Cephes/Eigen pexp, as in llvm_ir_runtime.cc)
__device__ __forceinline__ float xexp(float x) {
  x = fminf(x, 88.3762626647950f);
  x = fmaxf(x, -88.3762626647949f);
  float fx = floorf(__fadd_rn(__fmul_rn(x, 1.44269504088896341f), 0.5f));
  x = __fsub_rn(x, __fmul_rn(fx, 0.693359375f));
  x = __fsub_rn(x, __fmul_rn(fx, -2.12194440e-4f));
  float z = __fmul_rn(x, x);
  float y = 1.9875691500e-4f;
  y = __fadd_rn(__fmul_rn(y, x), 1.3981999507e-3f);
  y = __fadd_rn(__fmul_rn(y, x), 8.3334519073e-3f);
  y = __fadd_rn(__fmul_rn(y, x), 4.1665795894e-2f);
  y = __fadd_rn(__fmul_rn(y, x), 1.6666665459e-1f);
  y = __fadd_rn(__fmul_rn(y, x), 5.0000001201e-1f);
  y = __fadd_rn(__fmul_rn(y, z), x);
  y = __fadd_rn(y, 1.0f);
  int n = (int)fx;
  float p2n = __int_as_float((n + 127) << 23);
  return __fmul_rn(y, p2n);
}

// XLA logistic expansion: 1 / (1 + exp(-x)), IEEE divide
__device__ __forceinline__ float xsigmoid(float x) {
  float e = xexp(-x);
  return __fdiv_rn(1.0f, __fadd_rn(1.0f, e));
}

// Clone of XLA EmitFastTanh (Eigen ptanh rational approximation)
__device__ __forceinline__ float xtanh(float x) {
  float xc = fminf(fmaxf(x, -7.90531110763549805f), 7.90531110763549805f);
  float s = __fmul_rn(xc, xc);
  float p = -2.76076847742355e-16f;
  p = __fadd_rn(__fmul_rn(p, s), 2.00018790482477e-13f);
  p = __fadd_rn(__fmul_rn(p, s), -8.60467152213735e-11f);
  p = __fadd_rn(__fmul_rn(p, s), 5.12229709037114e-08f);
  p = __fadd_rn(__fmul_rn(p, s), 1.48572235717979e-05f);
  p = __fadd_rn(__fmul_rn(p, s), 6.37261928875436e-04f);
  p = __fadd_rn(__fmul_rn(p, s), 4.89352455891786e-03f);
  float num = __fmul_rn(xc, p);
  float q = 1.19825839466702e-06f;
  q = __fadd_rn(__fmul_rn(q, s), 1.18534705686654e-04f);
  q = __fadd_rn(__fmul_rn(q, s), 2.26843463243900e-03f);
  q = __fadd_rn(__fmul_rn(q, s), 4.89352518554385e-03f);
  float rat = __fdiv_rn(num, q);
  return (fabsf(x) < 0.0004f) ? x : rat;
}

// 2 waves/block, 2 rows/wave. Lane j owns hidden unit j for both rows.
// r,z weights (128 floats) in VGPRs; n-gate weights in LDS, transposed and
// pair-interleaved so lane j's ds_read_b64 is a free 2-way bank alias.
// Register demand ~220 < 256 => 2 waves/SIMD without AGPR round-trips
// (round-3's 1-wave/SIMD + AGPR-move tax) and without round-2's spill.
__global__ __launch_bounds__(128, 2) void gru_sample_kernel(
    const float* __restrict__ u, const float* __restrict__ w_ih,
    const float* __restrict__ w_hh, const float* __restrict__ b_ih,
    const float* __restrict__ b_hh, const float* __restrict__ head_w,
    const float* __restrict__ head_b, int* __restrict__ out) {
  const int lane = threadIdx.x & 63;
  const int wv = threadIdx.x >> 6;   // 0..1
  const int rowA = blockIdx.x * 4 + wv * 2;
  const int rowB = rowA + 1;

  __shared__ float2 wnp[NH / 2][NH];  // [k2][j] = {w_n[j][2k2], w_n[j][2k2+1]}
  __shared__ float hbuf[2][2][NH];
  float* hbA = hbuf[wv][0];
  float* hbB = hbuf[wv][1];

  // r,z weight rows in registers: w_hh[(g*64+lane)][k], k = 0..63
  float w_r[NH], w_z[NH];
#pragma unroll
  for (int kq = 0; kq < 16; ++kq) {
    float4 a = *(const float4*)&w_hh[(size_t)(lane)*NH + kq * 4];
    float4 b = *(const float4*)&w_hh[(size_t)(64 + lane) * NH + kq * 4];
    w_r[kq * 4 + 0] = a.x; w_r[kq * 4 + 1] = a.y; w_r[kq * 4 + 2] = a.z; w_r[kq * 4 + 3] = a.w;
    w_z[kq * 4 + 0] = b.x; w_z[kq * 4 + 1] = b.y; w_z[kq * 4 + 2] = b.z; w_z[kq * 4 + 3] = b.w;
  }
  // n-gate weights -> LDS (each wave fills half the k2 range)
#pragma unroll
  for (int k2 = 0; k2 < 16; ++k2) {
    int kk = wv * 16 + k2;
    wnp[kk][lane] = *(const float2*)&w_hh[(size_t)(128 + lane) * NH + 2 * kk];
  }
  const float bih_r = b_ih[lane], bih_z = b_ih[64 + lane], bih_n = b_ih[128 + lane];
  const float bhh_r = b_hh[lane], bhh_z = b_hh[64 + lane], bhh_n = b_hh[128 + lane];
  // prev ∈ {0,1}: gx = prev*w_ih + b_ih == (prev ? w_ih+b_ih : b_ih) bit-exactly.
  const float sum_r = __fadd_rn(w_ih[lane], bih_r);
  const float sum_z = __fadd_rn(w_ih[64 + lane], bih_z);
  const float sum_n = __fadd_rn(w_ih[128 + lane], bih_n);
  const float hw = head_w[lane];
  const float hb = head_b[0];
  __syncthreads();  // wnp ready (only cross-wave LDS dependency in kernel)

  const float* urA = u + (size_t)rowA * NS;
  const float* urB = u + (size_t)rowB * NS;
  int* orA = out + (size_t)rowA * NS;
  int* orB = out + (size_t)rowB * NS;

  float hA = 0.0f, hB = 0.0f;
  int prevA = 0, prevB = 0;
  hbA[lane] = 0.0f;
  hbB[lane] = 0.0f;

  float uA_cur = urA[lane];
  float uB_cur = urB[lane];
  for (int c = 0; c < 16; ++c) {
    float uA_next = (c < 15) ? urA[(c + 1) * 64 + lane] : 0.0f;
    float uB_next = (c < 15) ? urB[(c + 1) * 64 + lane] : 0.0f;
    int mybitA = 0, mybitB = 0;
    for (int tt = 0; tt < 64; ++tt) {
      // gh = h @ w_hh.T for both rows: sequential-k FMA from 0 (Eigen gebp)
      float arA = 0.0f, azA = 0.0f, anA = 0.0f;
      float arB = 0.0f, azB = 0.0f, anB = 0.0f;
#pragma unroll
      for (int kq = 0; kq < 16; ++kq) {
        float4 hvA = *(const float4*)&hbA[kq * 4];  // uniform-addr broadcast
        float4 hvB = *(const float4*)&hbB[kq * 4];
        float2 wn01 = wnp[2 * kq][lane];     // n-weights k=4kq..4kq+1
        float2 wn23 = wnp[2 * kq + 1][lane]; // n-weights k=4kq+2..4kq+3
        float w0 = w_r[kq * 4 + 0], w1 = w_r[kq * 4 + 1], w2 = w_r[kq * 4 + 2], w3 = w_r[kq * 4 + 3];
        arA = fmaf(hvA.x, w0, arA); arB = fmaf(hvB.x, w0, arB);
        arA = fmaf(hvA.y, w1, arA); arB = fmaf(hvB.y, w1, arB);
        arA = fmaf(hvA.z, w2, arA); arB = fmaf(hvB.z, w2, arB);
        arA = fmaf(hvA.w, w3, arA); arB = fmaf(hvB.w, w3, arB);
        w0 = w_z[kq * 4 + 0]; w1 = w_z[kq * 4 + 1]; w2 = w_z[kq * 4 + 2]; w3 = w_z[kq * 4 + 3];
        azA = fmaf(hvA.x, w0, azA); azB = fmaf(hvB.x, w0, azB);
        azA = fmaf(hvA.y, w1, azA); azB = fmaf(hvB.y, w1, azB);
        azA = fmaf(hvA.z, w2, azA); azB = fmaf(hvB.z, w2, azB);
        azA = fmaf(hvA.w, w3, azA); azB = fmaf(hvB.w, w3, azB);
        anA = fmaf(hvA.x, wn01.x, anA); anB = fmaf(hvB.x, wn01.x, anB);
        anA = fmaf(hvA.y, wn01.y, anA); anB = fmaf(hvB.y, wn01.y, anB);
        anA = fmaf(hvA.z, wn23.x, anA); anB = fmaf(hvB.z, wn23.x, anB);
        anA = fmaf(hvA.w, wn23.y, anA); anB = fmaf(hvB.w, wn23.y, anB);
      }
      // gates, exact reference association
      float ghnA = __fadd_rn(anA, bhh_n);
      float ghnB = __fadd_rn(anB, bhh_n);
      float rA = xsigmoid(__fadd_rn(prevA ? sum_r : bih_r, __fadd_rn(arA, bhh_r)));
      float rB = xsigmoid(__fadd_rn(prevB ? sum_r : bih_r, __fadd_rn(arB, bhh_r)));
      float zA = xsigmoid(__fadd_rn(prevA ? sum_z : bih_z, __fadd_rn(azA, bhh_z)));
      float zB = xsigmoid(__fadd_rn(prevB ? sum_z : bih_z, __fadd_rn(azB, bhh_z)));
      float nA = xtanh(__fadd_rn(prevA ? sum_n : bih_n, __fmul_rn(rA, ghnA)));
      float nB = xtanh(__fadd_rn(prevB ? sum_n : bih_n, __fmul_rn(rB, ghnB)));
      hA = __fadd_rn(__fmul_rn(__fsub_rn(1.0f, zA), nA), __fmul_rn(zA, hA));
      hB = __fadd_rn(__fmul_rn(__fsub_rn(1.0f, zB), nB), __fmul_rn(zB, hB));
      hbA[lane] = hA;
      hbB[lane] = hB;

      // head gemv clone per row: width-16 chunks then halving tree
      float PA = __fmul_rn(hA, hw);
      float PB = __fmul_rn(hB, hw);
      float sA = __fadd_rn(PA, __shfl(PA, lane + 16));
      float sB = __fadd_rn(PB, __shfl(PB, lane + 16));
      sA = __fadd_rn(sA, __shfl(PA, lane + 32));
      sB = __fadd_rn(sB, __shfl(PB, lane + 32));
      sA = __fadd_rn(sA, __shfl(PA, lane + 48));
      sB = __fadd_rn(sB, __shfl(PB, lane + 48));
      sA = __fadd_rn(sA, __shfl(sA, lane + 8));
      sB = __fadd_rn(sB, __shfl(sB, lane + 8));
      sA = __fadd_rn(sA, __shfl(sA, lane + 4));
      sB = __fadd_rn(sB, __shfl(sB, lane + 4));
      sA = __fadd_rn(sA, __shfl(sA, lane + 2));
      sB = __fadd_rn(sB, __shfl(sB, lane + 2));
      sA = __fadd_rn(sA, __shfl(sA, lane + 1));
      sB = __fadd_rn(sB, __shfl(sB, lane + 1));
      float logitA = __fadd_rn(__shfl(sA, 0), hb);
      float logitB = __fadd_rn(__shfl(sB, 0), hb);

      // packed head sigmoid: one instruction stream serves both rows
      float lg = (lane < 32) ? logitA : logitB;
      float pp = xsigmoid(lg);
      float pA = __shfl(pp, 0);
      float pB = __shfl(pp, 32);

      float uAt = __shfl(uA_cur, tt);
      float uBt = __shfl(uB_cur, tt);
      int bA = (uAt < pA) ? 1 : 0;
      int bB = (uBt < pB) ? 1 : 0;
      prevA = bA;
      prevB = bB;
      mybitA = (lane == tt) ? bA : mybitA;
      mybitB = (lane == tt) ? bB : mybitB;
    }
    orA[c * 64 + lane] = mybitA;
    orB[c * 64 + lane] = mybitB;
    uA_cur = uA_next;
    uB_cur = uB_next;
  }
}

extern "C" void kernel_launch(void* const* d_in, const int* in_sizes, int n_in,
                              void* d_out, int out_size, void* d_ws, size_t ws_size,
                              hipStream_t stream) {
  const float* u = (const float*)d_in[0];
  const float* w_ih = (const float*)d_in[1];
  const float* w_hh = (const float*)d_in[2];
  const float* b_ih = (const float*)d_in[3];
  const float* b_hh = (const float*)d_in[4];
  const float* head_w = (const float*)d_in[5];
  const float* head_b = (const float*)d_in[6];
  int* out = (int*)d_out;
  dim3 grid(NB / 4), block(128);
  gru_sample_kernel<<<grid, block, 0, stream>>>(u, w_ih, w_hh, b_ih, b_hh,
                                                head_w, head_b, out);
}

// Round 5
// 8400.527 us; speedup vs baseline: 3.2917x; 3.2917x over previous
//
#include <hip/hip_runtime.h>

#define NS 1024
#define NH 64
#define NB 16384

// ---- XLA-CPU fp32 op clones (no FP contraction: __fmul_rn/__fadd_rn) ----

// Clone of XLA GenerateVF32Exp (Cephes/Eigen pexp, as in llvm_ir_runtime.cc)
__device__ __forceinline__ float xexp(float x) {
  x = fminf(x, 88.3762626647950f);
  x = fmaxf(x, -88.3762626647949f);
  float fx = floorf(__fadd_rn(__fmul_rn(x, 1.44269504088896341f), 0.5f));
  x = __fsub_rn(x, __fmul_rn(fx, 0.693359375f));
  x = __fsub_rn(x, __fmul_rn(fx, -2.12194440e-4f));
  float z = __fmul_rn(x, x);
  float y = 1.9875691500e-4f;
  y = __fadd_rn(__fmul_rn(y, x), 1.3981999507e-3f);
  y = __fadd_rn(__fmul_rn(y, x), 8.3334519073e-3f);
  y = __fadd_rn(__fmul_rn(y, x), 4.1665795894e-2f);
  y = __fadd_rn(__fmul_rn(y, x), 1.6666665459e-1f);
  y = __fadd_rn(__fmul_rn(y, x), 5.0000001201e-1f);
  y = __fadd_rn(__fmul_rn(y, z), x);
  y = __fadd_rn(y, 1.0f);
  int n = (int)fx;
  float p2n = __int_as_float((n + 127) << 23);
  return __fmul_rn(y, p2n);
}

// XLA logistic expansion: 1 / (1 + exp(-x)), IEEE divide
__device__ __forceinline__ float xsigmoid(float x) {
  float e = xexp(-x);
  return __fdiv_rn(1.0f, __fadd_rn(1.0f, e));
}

// Clone of XLA EmitFastTanh (Eigen ptanh rational approximation)
__device__ __forceinline__ float xtanh(float x) {
  float xc = fminf(fmaxf(x, -7.90531110763549805f), 7.90531110763549805f);
  float s = __fmul_rn(xc, xc);
  float p = -2.76076847742355e-16f;
  p = __fadd_rn(__fmul_rn(p, s), 2.00018790482477e-13f);
  p = __fadd_rn(__fmul_rn(p, s), -8.60467152213735e-11f);
  p = __fadd_rn(__fmul_rn(p, s), 5.12229709037114e-08f);
  p = __fadd_rn(__fmul_rn(p, s), 1.48572235717979e-05f);
  p = __fadd_rn(__fmul_rn(p, s), 6.37261928875436e-04f);
  p = __fadd_rn(__fmul_rn(p, s), 4.89352455891786e-03f);
  float num = __fmul_rn(xc, p);
  float q = 1.19825839466702e-06f;
  q = __fadd_rn(__fmul_rn(q, s), 1.18534705686654e-04f);
  q = __fadd_rn(__fmul_rn(q, s), 2.26843463243900e-03f);
  q = __fadd_rn(__fmul_rn(q, s), 4.89352518554385e-03f);
  float rat = __fdiv_rn(num, q);
  return (fabsf(x) < 0.0004f) ? x : rat;
}

// ONE wave per block, ONE row per wave (R1's proven structure). Lane j owns
// hidden unit j. r,z weights (128 floats) in VGPRs; n-gate weights in LDS
// (float4 lane-contiguous layout -> optimal 1KB ds_read_b128 pattern).
// Register demand ~200 < 256 cap from launch_bounds(64,2) => 2 waves/SIMD
// with no AGPR round-trips (R1's tax) and no scratch spill (R2/R4's bug).
// Single-wave block: wnq filled and read by the same wave -> zero barriers.
__global__ __launch_bounds__(64, 2) void gru_sample_kernel(
    const float* __restrict__ u, const float* __restrict__ w_ih,
    const float* __restrict__ w_hh, const float* __restrict__ b_ih,
    const float* __restrict__ b_hh, const float* __restrict__ head_w,
    const float* __restrict__ head_b, int* __restrict__ out) {
  const int lane = threadIdx.x;
  const int row = blockIdx.x;

  __shared__ float4 wnq[16][NH];  // [k4][j] = w_n[j][4k4 .. 4k4+3]
  __shared__ float hb_[NH];

  // r,z weight rows in registers: w_hh[(g*64+lane)][k], k = 0..63
  float w_r[NH], w_z[NH];
#pragma unroll
  for (int kq = 0; kq < 16; ++kq) {
    float4 a = *(const float4*)&w_hh[(size_t)(lane)*NH + kq * 4];
    float4 b = *(const float4*)&w_hh[(size_t)(64 + lane) * NH + kq * 4];
    w_r[kq * 4 + 0] = a.x; w_r[kq * 4 + 1] = a.y; w_r[kq * 4 + 2] = a.z; w_r[kq * 4 + 3] = a.w;
    w_z[kq * 4 + 0] = b.x; w_z[kq * 4 + 1] = b.y; w_z[kq * 4 + 2] = b.z; w_z[kq * 4 + 3] = b.w;
  }
  // n-gate weights -> LDS (same wave fills and reads: no barrier needed)
#pragma unroll
  for (int k4 = 0; k4 < 16; ++k4) {
    wnq[k4][lane] = *(const float4*)&w_hh[(size_t)(128 + lane) * NH + 4 * k4];
  }
  const float bih_r = b_ih[lane], bih_z = b_ih[64 + lane], bih_n = b_ih[128 + lane];
  const float bhh_r = b_hh[lane], bhh_z = b_hh[64 + lane], bhh_n = b_hh[128 + lane];
  // prev ∈ {0,1}: gx = prev*w_ih + b_ih == (prev ? w_ih+b_ih : b_ih) bit-exactly.
  const float sum_r = __fadd_rn(w_ih[lane], bih_r);
  const float sum_z = __fadd_rn(w_ih[64 + lane], bih_z);
  const float sum_n = __fadd_rn(w_ih[128 + lane], bih_n);
  const float hw = head_w[lane];
  const float hb = head_b[0];

  const float* urow = u + (size_t)row * NS;
  int* orow = out + (size_t)row * NS;

  float h = 0.0f;
  int prev = 0;
  hb_[lane] = 0.0f;

  float u_cur = urow[lane];
  for (int c = 0; c < 16; ++c) {
    float u_next = (c < 15) ? urow[(c + 1) * 64 + lane] : 0.0f;
    int mybit = 0;
    for (int tt = 0; tt < 64; ++tt) {
      // gh = h @ w_hh.T : sequential-k FMA from 0 (Eigen gebp clone)
      float ar = 0.0f, az = 0.0f, an = 0.0f;
#pragma unroll
      for (int kq = 0; kq < 16; ++kq) {
        float4 hv = *(const float4*)&hb_[kq * 4];  // uniform-addr broadcast
        float4 wn = wnq[kq][lane];                 // lane-contiguous b128
        ar = fmaf(hv.x, w_r[kq * 4 + 0], ar);
        ar = fmaf(hv.y, w_r[kq * 4 + 1], ar);
        ar = fmaf(hv.z, w_r[kq * 4 + 2], ar);
        ar = fmaf(hv.w, w_r[kq * 4 + 3], ar);
        az = fmaf(hv.x, w_z[kq * 4 + 0], az);
        az = fmaf(hv.y, w_z[kq * 4 + 1], az);
        az = fmaf(hv.z, w_z[kq * 4 + 2], az);
        az = fmaf(hv.w, w_z[kq * 4 + 3], az);
        an = fmaf(hv.x, wn.x, an);
        an = fmaf(hv.y, wn.y, an);
        an = fmaf(hv.z, wn.z, an);
        an = fmaf(hv.w, wn.w, an);
      }
      // gates, exact reference association
      float gh_r = __fadd_rn(ar, bhh_r);
      float gh_z = __fadd_rn(az, bhh_z);
      float gh_n = __fadd_rn(an, bhh_n);
      float r = xsigmoid(__fadd_rn(prev ? sum_r : bih_r, gh_r));
      float z = xsigmoid(__fadd_rn(prev ? sum_z : bih_z, gh_z));
      float n = xtanh(__fadd_rn(prev ? sum_n : bih_n, __fmul_rn(r, gh_n)));
      h = __fadd_rn(__fmul_rn(__fsub_rn(1.0f, z), n), __fmul_rn(z, h));
      hb_[lane] = h;  // for next step's matvec

      // head gemv clone: width-16 chunks (mul + ordered adds), halving tree
      float P = __fmul_rn(h, hw);
      float s = __fadd_rn(P, __shfl(P, lane + 16));
      s = __fadd_rn(s, __shfl(P, lane + 32));
      s = __fadd_rn(s, __shfl(P, lane + 48));
      s = __fadd_rn(s, __shfl(s, lane + 8));
      s = __fadd_rn(s, __shfl(s, lane + 4));
      s = __fadd_rn(s, __shfl(s, lane + 2));
      s = __fadd_rn(s, __shfl(s, lane + 1));
      float logit = __fadd_rn(__shfl(s, 0), hb);
      float p = xsigmoid(logit);  // wave-uniform, all lanes redundant

      float u_t = __shfl(u_cur, tt);
      int b = (u_t < p) ? 1 : 0;
      prev = b;
      mybit = (lane == tt) ? b : mybit;
    }
    orow[c * 64 + lane] = mybit;  // coalesced per 64-step chunk
    u_cur = u_next;
  }
}

extern "C" void kernel_launch(void* const* d_in, const int* in_sizes, int n_in,
                              void* d_out, int out_size, void* d_ws, size_t ws_size,
                              hipStream_t stream) {
  const float* u = (const float*)d_in[0];
  const float* w_ih = (const float*)d_in[1];
  const float* w_hh = (const float*)d_in[2];
  const float* b_ih = (const float*)d_in[3];
  const float* b_hh = (const float*)d_in[4];
  const float* head_w = (const float*)d_in[5];
  const float* head_b = (const float*)d_in[6];
  int* out = (int*)d_out;
  dim3 grid(NB), block(64);
  gru_sample_kernel<<<grid, block, 0, stream>>>(u, w_ih, w_hh, b_ih, b_hh,
                                                head_w, head_b, out);
}